// Round 17
// baseline (137.731 us; speedup 1.0000x reference)
//
#include <hip/hip_runtime.h>

typedef unsigned short u16;
typedef unsigned int u32;
typedef __attribute__((ext_vector_type(8))) short short8;
typedef __attribute__((ext_vector_type(4))) short short4v;
typedef __attribute__((ext_vector_type(4))) float f32x4;
typedef __attribute__((ext_vector_type(16))) float f32x16;
typedef __attribute__((ext_vector_type(2))) unsigned u32x2;
typedef __attribute__((ext_vector_type(4))) unsigned u32x4;

__device__ __forceinline__ u16 f2bf(float f) {
  union { float f; unsigned u; } a; a.f = f;
  unsigned u = a.u + 0x7fffu + ((a.u >> 16) & 1u);
  return (u16)(u >> 16);
}
__device__ __forceinline__ float bf2f(short s) {
  union { unsigned u; float f; } a; a.u = ((unsigned)(unsigned short)s) << 16;
  return a.f;
}
__device__ __forceinline__ u32 cvtpk(float lo, float hi_) {
  u32 r; asm("v_cvt_pk_bf16_f32 %0, %1, %2" : "=v"(r) : "v"(lo), "v"(hi_)); return r;
}
// plswap(P,Q): P' = [P_lo | Q_lo], Q' = [P_hi | Q_hi]  (R10-verified on HW)
__device__ __forceinline__ void plswap(u32 &x, u32 &y) {
  asm("v_permlane32_swap_b32 %0, %1" : "+v"(x), "+v"(y));
}
__device__ __forceinline__ short8 as_short8(u32x4 v) {
  union { u32x4 u; short8 s; } c; c.u = v; return c.s;
}
// raw single-instruction exp2 (inputs small & finite here)
__device__ __forceinline__ float fexp2(float x) {
  float r; asm("v_exp_f32 %0, %1" : "=v"(r) : "v"(x)); return r;
}
__device__ __forceinline__ void gload16(const u16* g, u16* l) {
  __builtin_amdgcn_global_load_lds(
      (__attribute__((address_space(1))) void*)(u16*)g,
      (__attribute__((address_space(3))) void*)l, 16, 0, 0);
}
__device__ __forceinline__ void keep8(short8 v) {
  union { short8 s; int i[4]; } u; u.s = v;
  asm volatile("" :: "v"(u.i[0]), "v"(u.i[1]), "v"(u.i[2]), "v"(u.i[3]));
}
__device__ __forceinline__ void wait_vm6() { asm volatile("s_waitcnt vmcnt(6)" ::: "memory"); }
__device__ __forceinline__ void wait_vm4() { asm volatile("s_waitcnt vmcnt(4)" ::: "memory"); }
__device__ __forceinline__ void wait_vm2() { asm volatile("s_waitcnt vmcnt(2)" ::: "memory"); }
__device__ __forceinline__ void wait_vm0() { asm volatile("s_waitcnt vmcnt(0)" ::: "memory"); }
__device__ __forceinline__ void wait_lgkm0() { asm volatile("s_waitcnt lgkmcnt(0)" ::: "memory"); }
__device__ __forceinline__ void barrier_raw() {
  __builtin_amdgcn_sched_barrier(0);
  __builtin_amdgcn_s_barrier();
  __builtin_amdgcn_sched_barrier(0);
}

// ---------------- fused: x->bf16 convert  +  weight prep ----------------
__global__ void cvtprep_kernel(const float* __restrict__ x, u16* __restrict__ xb,
                               const float* __restrict__ Wq, const float* __restrict__ Wk,
                               const float* __restrict__ Wv, const float* __restrict__ Wo,
                               const float* __restrict__ qw,
                               u16* __restrict__ Wcat, u16* __restrict__ Wot) {
  __shared__ float tile[32][33];
  const int blk = blockIdx.x;
  const int tid = threadIdx.x;
  if (blk < 2048) {
    int i = (blk * 256 + tid) * 8;
    float4 a = *(const float4*)(x + i);
    float4 b = *(const float4*)(x + i + 4);
    short8 v;
    v[0] = (short)f2bf(a.x); v[1] = (short)f2bf(a.y);
    v[2] = (short)f2bf(a.z); v[3] = (short)f2bf(a.w);
    v[4] = (short)f2bf(b.x); v[5] = (short)f2bf(b.y);
    v[6] = (short)f2bf(b.z); v[7] = (short)f2bf(b.w);
    *(short8*)(xb + i) = v;
    return;
  }
  const int pb = blk - 2048;
  const int z = pb >> 10;
  const int xy = pb & 1023;
  const int n0 = (xy & 31) * 32, k0 = (xy >> 5) * 32;
  const int tx = tid & 31, ty = tid >> 5;          // 32 x 8
  const float* src = (z == 0) ? Wq : (z == 1) ? Wk : (z == 2) ? Wv : Wo;
  float w0 = 0.f, w1 = 0.f, w2 = 0.f, w3 = 0.f;
  if (z == 1) {
    float a = qw[0], b = qw[1], c = qw[2], d = qw[3];
    float mx = fmaxf(fmaxf(a, b), fmaxf(c, d));
    float ea = expf(a - mx), eb = expf(b - mx), ec = expf(c - mx), ed = expf(d - mx);
    float s = ea + eb + ec + ed;
    w0 = ea / s; w1 = eb / s; w2 = ec / s; w3 = ed / s;
  }
  #pragma unroll
  for (int i = 0; i < 32; i += 8) {
    int k = k0 + ty + i;
    int n = n0 + tx;
    float v;
    if (z == 1) {
      int c = n & 63;
      if (c < 32) v = w0 * src[k * 1024 + n]      + w1 * src[k * 1024 + n + 32];
      else        v = w2 * src[k * 1024 + n - 32] + w3 * src[k * 1024 + n];
    } else {
      v = src[k * 1024 + n];
    }
    tile[ty + i][tx] = v;
  }
  __syncthreads();
  #pragma unroll
  for (int i = 0; i < 32; i += 8) {
    int n = n0 + ty + i;
    int k = k0 + tx;
    u16 v = f2bf(tile[tx][ty + i]);
    if (z < 3) Wcat[(size_t)(z * 1024 + n) * 1024 + k] = v;
    else       Wot[(size_t)n * 1024 + k] = v;
  }
}

// ---------------- GEMM0 (R7/R13-proven): tri-buffered counted-vmcnt pipeline, BK=32 ----------------
template<int BM>
__global__ __launch_bounds__(256, 2)
void gemm_k(const u16* __restrict__ A, const u16* __restrict__ Bm,
            u16* __restrict__ out_q, u16* __restrict__ out_k,
            u16* __restrict__ out_vt) {
  constexpr int WM = BM / 2;
  constexpr int MR = WM / 16;
  constexpr int RW = BM / 4;
  __shared__ u16 At[3][BM * 32];
  __shared__ u16 Bt[3][128 * 32];
  const int tid = threadIdx.x;
  const int wid = tid >> 6, lane = tid & 63;
  const int l15 = lane & 15, l4 = lane >> 4;

  const int nwg = gridDim.x * gridDim.y;
  const int cpx = nwg >> 3;
  int bid = blockIdx.y * gridDim.x + blockIdx.x;
  int wg = (bid & 7) * cpx + (bid >> 3);
  const int bx = wg % gridDim.x, by = wg / gridDim.x;
  const int mblk = by * BM, nblk = bx * 128;
  const int wm = (wid >> 1) * WM, wn = (wid & 1) * 64;
  f32x4 acc[MR][4] = {};

  const int rr = lane >> 2;
  const int cA = (lane & 3) * 8;
  const u16* gB = Bm + (size_t)(nblk + wid * 32 + rr) * 1024 + cA;
  const u16* gA = A + (size_t)(mblk + wid * RW + rr) * 1024 + cA;

  auto STAGE = [&](int ib, int kt) {
    #pragma unroll
    for (int q = 0; q < RW / 16; ++q)
      gload16(gA + (size_t)q * 16 * 1024 + kt, &At[ib][(wid * RW + q * 16) * 32]);
    #pragma unroll
    for (int q = 0; q < 2; ++q)
      gload16(gB + (size_t)q * 16 * 1024 + kt, &Bt[ib][(wid * 32 + q * 16) * 32]);
  };

  STAGE(0, 0);
  STAGE(1, 32);
  int ib = 0, ibw = 2;
  for (int s = 0; s < 32; ++s) {
    if (s < 31) wait_vm4(); else wait_vm0();
    barrier_raw();
    if (s + 2 < 32) STAGE(ibw, (s + 2) * 32);
    short8 af[MR], bf[4];
    #pragma unroll
    for (int i = 0; i < MR; ++i)
      af[i] = *(const short8*)(&At[ib][(wm + i * 16 + l15) * 32 + l4 * 8]);
    #pragma unroll
    for (int j = 0; j < 4; ++j)
      bf[j] = *(const short8*)(&Bt[ib][(wn + j * 16 + l15) * 32 + l4 * 8]);
    #pragma unroll
    for (int i = 0; i < MR; ++i)
      #pragma unroll
      for (int j = 0; j < 4; ++j)
        acc[i][j] = __builtin_amdgcn_mfma_f32_16x16x32_bf16(af[i], bf[j], acc[i][j], 0, 0, 0);
    ib = (ib == 2) ? 0 : ib + 1;
    ibw = (ibw == 2) ? 0 : ibw + 1;
  }

  const float QSCALE = 0.17677669529663687f * 1.4426950408889634f; // 32^-0.5 * log2(e)
  #pragma unroll
  for (int i = 0; i < MR; ++i) {
    int m_g = mblk + wm + i * 16 + l4 * 4;
    #pragma unroll
    for (int j = 0; j < 4; ++j) {
      int n_g = nblk + wn + j * 16 + l15;
      f32x4 v = acc[i][j];
      if (n_g < 2048) {
        u16* dst; float sc;
        if (n_g < 1024) { dst = out_q; sc = QSCALE; } else { dst = out_k; sc = 1.0f; }
        int nn = n_g & 1023;
        #pragma unroll
        for (int jj = 0; jj < 4; ++jj)
          dst[(size_t)(m_g + jj) * 1024 + nn] = f2bf(v[jj] * sc);
      } else {
        int c = n_g - 2048;
        int b = m_g >> 11, t = m_g & 2047;
        short4v p;
        p[0] = (short)f2bf(v[0]); p[1] = (short)f2bf(v[1]);
        p[2] = (short)f2bf(v[2]); p[3] = (short)f2bf(v[3]);
        *(short4v*)(out_vt + ((size_t)((b << 4) + (c >> 6)) * 64 + (c & 63)) * 2048 + t) = p;
      }
    }
  }
}

// ---------------- flash attention (R15-proven): no-max + split-KV 2-way ----------------
__global__ __launch_bounds__(256, 4)
void attn_k(const u16* __restrict__ Q, const u16* __restrict__ Kb,
            const u16* __restrict__ Vt, u16* __restrict__ Opart,
            float* __restrict__ L) {
  __shared__ u16 lk[2][64 * 64];
  __shared__ u16 lv[2][64 * 64];
  const int tid = threadIdx.x, wid = tid >> 6, lane = tid & 63;
  const int l31 = lane & 31, hi = lane >> 5;

  int bid = blockIdx.y * 16 + blockIdx.x;
  int wg = (bid & 7) * 128 + (bid >> 3);
  const int qt = wg & 15;
  const int yy = wg >> 4;
  const int half = yy & 1, bh = yy >> 1;
  const int b = bh >> 4, h = bh & 15;
  const int qrow = qt * 128 + wid * 32 + l31;

  short8 qf[4];
  #pragma unroll
  for (int cs = 0; cs < 4; ++cs)
    qf[cs] = *(const short8*)(Q + (size_t)(b * 2048 + qrow) * 1024 + h * 64 + cs * 16 + hi * 8);
  #pragma unroll
  for (int cs = 0; cs < 4; ++cs) keep8(qf[cs]);

  const int sr = lane >> 3;
  const int sc8 = (lane & 7) ^ sr;
  const u16* Kg = Kb + ((size_t)b * 2048 + half * 1024) * 1024 + h * 64 + sc8 * 8;
  const u16* Vg = Vt + (size_t)bh * 64 * 2048 + half * 1024 + sc8 * 8;
  const int s0i = wid * 2;
  const int swz = l31 & 7;

  short8 onesf;
  #pragma unroll
  for (int j = 0; j < 8; ++j) onesf[j] = (short)0x3F80;
  const f32x16 z16 = {};

  f32x16 accO0 = {}, accO1 = {}, sacc = {};

  auto STAGE = [&](int tt, int ibx) {
    #pragma unroll
    for (int s2 = 0; s2 < 2; ++s2) {
      int s = s0i + s2;
      int r = s * 8 + sr;
      gload16(Kg + (size_t)(tt * 64 + r) * 1024, &lk[ibx][s * 512]);
      gload16(Vg + (size_t)r * 2048 + tt * 64, &lv[ibx][s * 512]);
    }
  };

  STAGE(0, 0);

  for (int t = 0; t < 16; ++t) {
    wait_vm0();
    barrier_raw();
    if (t + 1 < 16) STAGE(t + 1, (t + 1) & 1);

    const u16* kb = lk[t & 1];
    const u16* vb = lv[t & 1];

    f32x16 s0v, s1v;
    __builtin_amdgcn_s_setprio(1);
    {
      short8 k0 = *(const short8*)(kb + l31 * 64 + ((hi ^ swz) * 8));
      short8 k1 = *(const short8*)(kb + (32 + l31) * 64 + ((hi ^ swz) * 8));
      s0v = __builtin_amdgcn_mfma_f32_32x32x16_bf16(k0, qf[0], z16, 0, 0, 0);
      s1v = __builtin_amdgcn_mfma_f32_32x32x16_bf16(k1, qf[0], z16, 0, 0, 0);
    }
    #pragma unroll
    for (int cs = 1; cs < 4; ++cs) {
      int ch = cs * 2 + hi;
      short8 k0 = *(const short8*)(kb + l31 * 64 + ((ch ^ swz) * 8));
      short8 k1 = *(const short8*)(kb + (32 + l31) * 64 + ((ch ^ swz) * 8));
      s0v = __builtin_amdgcn_mfma_f32_32x32x16_bf16(k0, qf[cs], s0v, 0, 0, 0);
      s1v = __builtin_amdgcn_mfma_f32_32x32x16_bf16(k1, qf[cs], s1v, 0, 0, 0);
    }
    __builtin_amdgcn_s_setprio(0);

    #pragma unroll
    for (int i = 0; i < 16; ++i) { s0v[i] = fexp2(s0v[i]); s1v[i] = fexp2(s1v[i]); }

    short8 paS[4];
    #pragma unroll
    for (int hf = 0; hf < 2; ++hf) {
      #pragma unroll
      for (int kq = 0; kq < 2; ++kq) {
        float p0, p1, p2, p3, p4, p5, p6, p7;
        if (hf == 0) {
          p0 = s0v[kq*8+0]; p1 = s0v[kq*8+1]; p2 = s0v[kq*8+2]; p3 = s0v[kq*8+3];
          p4 = s0v[kq*8+4]; p5 = s0v[kq*8+5]; p6 = s0v[kq*8+6]; p7 = s0v[kq*8+7];
        } else {
          p0 = s1v[kq*8+0]; p1 = s1v[kq*8+1]; p2 = s1v[kq*8+2]; p3 = s1v[kq*8+3];
          p4 = s1v[kq*8+4]; p5 = s1v[kq*8+5]; p6 = s1v[kq*8+6]; p7 = s1v[kq*8+7];
        }
        u32 A = cvtpk(p0, p1), B = cvtpk(p2, p3);
        u32 C = cvtpk(p4, p5), D = cvtpk(p6, p7);
        plswap(A, C);
        plswap(B, D);
        u32x4 w; w[0] = A; w[1] = B; w[2] = C; w[3] = D;
        paS[hf * 2 + kq] = as_short8(w);
      }
    }

    __builtin_amdgcn_s_setprio(1);
    #pragma unroll
    for (int ks = 0; ks < 4; ++ks) {
      int ch = ks * 2 + hi;
      short8 v0 = *(const short8*)(vb + l31 * 64 + ((ch ^ swz) * 8));
      short8 v1 = *(const short8*)(vb + (32 + l31) * 64 + ((ch ^ swz) * 8));
      accO0 = __builtin_amdgcn_mfma_f32_32x32x16_bf16(v0, paS[ks], accO0, 0, 0, 0);
      accO1 = __builtin_amdgcn_mfma_f32_32x32x16_bf16(v1, paS[ks], accO1, 0, 0, 0);
      sacc  = __builtin_amdgcn_mfma_f32_32x32x16_bf16(onesf, paS[ks], sacc, 0, 0, 0);
    }
    __builtin_amdgcn_s_setprio(0);
  }

  u16* Po = Opart + (size_t)(half * 4096 + b * 2048 + qrow) * 1024 + h * 64;
  #pragma unroll
  for (int g = 0; g < 4; ++g) {
    u32x2 pr;
    pr[0] = cvtpk(accO0[4*g],    accO0[4*g+1]);
    pr[1] = cvtpk(accO0[4*g+2],  accO0[4*g+3]);
    *(u32x2*)(Po + 8*g + 4*hi) = pr;
    u32x2 pr2;
    pr2[0] = cvtpk(accO1[4*g],   accO1[4*g+1]);
    pr2[1] = cvtpk(accO1[4*g+2], accO1[4*g+3]);
    *(u32x2*)(Po + 32 + 8*g + 4*hi) = pr2;
  }
  if (hi == 0)
    L[(size_t)(half * 32 + bh) * 2048 + qrow] = sacc[0];
}

// ---------------- GEMM1 fused with merge ----------------
// A' = (O1 + O2) * inv(row, head-of-k) staged at ds_write time. inv is per
// (A-row, INPUT-head = k>>6) — it does NOT commute to the output, so it is
// applied on the A side. head(tile) = tile>>1 is wave-uniform. Linv cached in LDS.
__global__ __launch_bounds__(256, 2)
void gemm1_fused(const u16* __restrict__ Op, const float* __restrict__ L,
                 const u16* __restrict__ Bm, float* __restrict__ out_f) {
  constexpr int BM = 64;
  constexpr int MR = 2;
  __shared__ u16 At[3][BM * 32];
  __shared__ u16 Bt[3][128 * 32];
  __shared__ float Linv[16 * 64];       // [head][row]
  const int tid = threadIdx.x;
  const int wid = tid >> 6, lane = tid & 63;
  const int l15 = lane & 15, l4 = lane >> 4;

  const int nwg = gridDim.x * gridDim.y;
  const int cpx = nwg >> 3;
  int bid = blockIdx.y * gridDim.x + blockIdx.x;
  int wg = (bid & 7) * cpx + (bid >> 3);
  const int bx = wg % gridDim.x, by = wg / gridDim.x;
  const int mblk = by * BM, nblk = bx * 128;
  const int wm = (wid >> 1) * 32, wn = (wid & 1) * 64;
  f32x4 acc[MR][4] = {};

  // ---- preload Linv = 1/(l1+l2) for 64 rows x 16 heads (drains before pipeline) ----
  {
    int h = tid >> 4;                 // 0..15
    int r0 = (tid & 15) * 4;          // 0..60
    int m0 = mblk + r0;
    int b0 = m0 >> 11, tr0 = m0 & 2047;
    int bh = b0 * 16 + h;
    float4 l1 = *(const float4*)(L + (size_t)bh * 2048 + tr0);
    float4 l2 = *(const float4*)(L + (size_t)(32 + bh) * 2048 + tr0);
    float4 iv;
    iv.x = 1.0f / (l1.x + l2.x); iv.y = 1.0f / (l1.y + l2.y);
    iv.z = 1.0f / (l1.z + l2.z); iv.w = 1.0f / (l1.w + l2.w);
    *(float4*)(&Linv[h * 64 + r0]) = iv;   // auto vmcnt-drain via register use
  }
  wait_lgkm0();
  barrier_raw();

  const int rr = lane >> 2;
  const int cA = (lane & 3) * 8;
  const int lrow = wid * 16 + rr;          // local A row this lane stages
  const u16* gA1 = Op + (size_t)(mblk + lrow) * 1024 + cA;   // half 0
  const u16* gA2 = gA1 + (size_t)4096 * 1024;                // half 1
  const u16* gB = Bm + (size_t)(nblk + wid * 32 + rr) * 1024 + cA;

  u32x4 rA1[2], rA2[2];

  auto LOADA = [&](int set, int kt) {
    rA1[set] = *(const u32x4*)(gA1 + kt);
    rA2[set] = *(const u32x4*)(gA2 + kt);
  };
  auto STAGEB = [&](int ib, int kt) {
    #pragma unroll
    for (int q = 0; q < 2; ++q)
      gload16(gB + (size_t)q * 16 * 1024 + kt, &Bt[ib][(wid * 32 + q * 16) * 32]);
  };
  auto WRITEA = [&](int set, int ib, int tile) {
    float inv = Linv[(tile >> 1) * 64 + lrow];   // broadcast ds_read (wave-uniform head)
    union { u32x4 u; short8 s; } a1, a2;
    a1.u = rA1[set]; a2.u = rA2[set];
    u32x4 w;
    #pragma unroll
    for (int j = 0; j < 4; ++j)
      w[j] = cvtpk((bf2f(a1.s[2*j])   + bf2f(a2.s[2*j]))   * inv,
                   (bf2f(a1.s[2*j+1]) + bf2f(a2.s[2*j+1])) * inv);
    *(u32x4*)(&At[ib][lrow * 32 + cA]) = w;
  };

  // prologue
  LOADA(0, 0);
  STAGEB(0, 0);
  LOADA(1, 32);
  STAGEB(1, 32);
  wait_vm6();              // Aregs(0) arrived; 6 left: B0, Aregs1, B1
  WRITEA(0, 0, 0);

  for (int s = 0; s < 32; ++s) {
    if (s < 30) wait_vm2(); else wait_vm0();
    wait_lgkm0();
    barrier_raw();
    if (s + 1 < 32) WRITEA((s + 1) & 1, (s + 1) % 3, s + 1);
    if (s + 2 < 32) {
      LOADA(s & 1, (s + 2) * 32);
      STAGEB((s + 2) % 3, (s + 2) * 32);
    }
    const int ib = s % 3;
    short8 af[MR], bf[4];
    #pragma unroll
    for (int i = 0; i < MR; ++i)
      af[i] = *(const short8*)(&At[ib][(wm + i * 16 + l15) * 32 + l4 * 8]);
    #pragma unroll
    for (int j = 0; j < 4; ++j)
      bf[j] = *(const short8*)(&Bt[ib][(wn + j * 16 + l15) * 32 + l4 * 8]);
    #pragma unroll
    for (int i = 0; i < MR; ++i)
      #pragma unroll
      for (int j = 0; j < 4; ++j)
        acc[i][j] = __builtin_amdgcn_mfma_f32_16x16x32_bf16(af[i], bf[j], acc[i][j], 0, 0, 0);
  }

  // epilogue: plain store (inv already applied on A side)
  #pragma unroll
  for (int i = 0; i < MR; ++i) {
    int m_g = mblk + wm + i * 16 + l4 * 4;
    #pragma unroll
    for (int j = 0; j < 4; ++j) {
      int n_g = nblk + wn + j * 16 + l15;
      f32x4 v = acc[i][j];
      #pragma unroll
      for (int jj = 0; jj < 4; ++jj)
        out_f[(size_t)(m_g + jj) * 1024 + n_g] = v[jj];
    }
  }
}

// ---------------- launch ----------------
// ws layout (43 MB, liveness-overlapped):
//  [0,2)   Wot        (prep -> gemm1)
//  [2,10)  Qb         (gemm0 -> attn)
//  [10,18) Kb         (gemm0 -> attn)
//  [18,26) Vtb        (gemm0 -> attn)
//  [26,34) xb         (cvt -> gemm0)    ... reused by Opart
//  [34,40) Wcat       (prep -> gemm0)   ... reused by Opart
//  [26,42) Opart bf16 (attn -> gemm1)
//  [42,43) L f32      (attn -> gemm1)
extern "C" void kernel_launch(void* const* d_in, const int* in_sizes, int n_in,
                              void* d_out, int out_size, void* d_ws, size_t ws_size,
                              hipStream_t stream) {
  const float* x  = (const float*)d_in[0];
  const float* Wq = (const float*)d_in[1];
  const float* Wk = (const float*)d_in[2];
  const float* Wv = (const float*)d_in[3];
  const float* Wo = (const float*)d_in[4];
  const float* qw = (const float*)d_in[5];

  char* w = (char*)d_ws;
  u16* Wot   = (u16*)(w);
  u16* Qb    = (u16*)(w + (2u  << 20));
  u16* Kb    = (u16*)(w + (10u << 20));
  u16* Vtb   = (u16*)(w + (18u << 20));
  u16* xb    = (u16*)(w + (26u << 20));
  u16* Wcat  = (u16*)(w + (34u << 20));
  u16* Opart = (u16*)(w + (26u << 20));
  float* L   = (float*)(w + (42u << 20));

  cvtprep_kernel<<<6144, 256, 0, stream>>>(x, xb, Wq, Wk, Wv, Wo, qw, Wcat, Wot);
  gemm_k<128><<<dim3(24, 32), 256, 0, stream>>>(xb, Wcat, Qb, Kb, Vtb);
  attn_k<<<dim3(16, 64), 256, 0, stream>>>(Qb, Kb, Vtb, Opart, L);
  gemm1_fused<<<dim3(8, 64), 256, 0, stream>>>(Opart, L, Wot, (float*)d_out);
}

// Round 18
// 120.427 us; speedup vs baseline: 1.1437x; 1.1437x over previous
//
#include <hip/hip_runtime.h>

typedef unsigned short u16;
typedef unsigned int u32;
typedef __attribute__((ext_vector_type(8))) short short8;
typedef __attribute__((ext_vector_type(4))) short short4v;
typedef __attribute__((ext_vector_type(4))) float f32x4;
typedef __attribute__((ext_vector_type(16))) float f32x16;
typedef __attribute__((ext_vector_type(2))) unsigned u32x2;
typedef __attribute__((ext_vector_type(4))) unsigned u32x4;

__device__ __forceinline__ u16 f2bf(float f) {
  union { float f; unsigned u; } a; a.f = f;
  unsigned u = a.u + 0x7fffu + ((a.u >> 16) & 1u);
  return (u16)(u >> 16);
}
__device__ __forceinline__ float bf2f(short s) {
  union { unsigned u; float f; } a; a.u = ((unsigned)(unsigned short)s) << 16;
  return a.f;
}
__device__ __forceinline__ u32 cvtpk(float lo, float hi_) {
  u32 r; asm("v_cvt_pk_bf16_f32 %0, %1, %2" : "=v"(r) : "v"(lo), "v"(hi_)); return r;
}
// plswap(P,Q): P' = [P_lo | Q_lo], Q' = [P_hi | Q_hi]  (R10-verified on HW)
__device__ __forceinline__ void plswap(u32 &x, u32 &y) {
  asm("v_permlane32_swap_b32 %0, %1" : "+v"(x), "+v"(y));
}
__device__ __forceinline__ short8 as_short8(u32x4 v) {
  union { u32x4 u; short8 s; } c; c.u = v; return c.s;
}
// raw single-instruction exp2 (inputs small & finite here)
__device__ __forceinline__ float fexp2(float x) {
  float r; asm("v_exp_f32 %0, %1" : "=v"(r) : "v"(x)); return r;
}
__device__ __forceinline__ void gload16(const u16* g, u16* l) {
  __builtin_amdgcn_global_load_lds(
      (__attribute__((address_space(1))) void*)(u16*)g,
      (__attribute__((address_space(3))) void*)l, 16, 0, 0);
}
__device__ __forceinline__ void keep8(short8 v) {
  union { short8 s; int i[4]; } u; u.s = v;
  asm volatile("" :: "v"(u.i[0]), "v"(u.i[1]), "v"(u.i[2]), "v"(u.i[3]));
}
__device__ __forceinline__ void wait_vm4() { asm volatile("s_waitcnt vmcnt(4)" ::: "memory"); }
__device__ __forceinline__ void wait_vm3() { asm volatile("s_waitcnt vmcnt(3)" ::: "memory"); }
__device__ __forceinline__ void wait_vm0() { asm volatile("s_waitcnt vmcnt(0)" ::: "memory"); }
__device__ __forceinline__ void barrier_raw() {
  __builtin_amdgcn_sched_barrier(0);
  __builtin_amdgcn_s_barrier();
  __builtin_amdgcn_sched_barrier(0);
}

// ---------------- fused: x->bf16 convert + weight prep (R17-proven) ----------------
__global__ void cvtprep_kernel(const float* __restrict__ x, u16* __restrict__ xb,
                               const float* __restrict__ Wq, const float* __restrict__ Wk,
                               const float* __restrict__ Wv, const float* __restrict__ Wo,
                               const float* __restrict__ qw,
                               u16* __restrict__ Wcat, u16* __restrict__ Wot) {
  __shared__ float tile[32][33];
  const int blk = blockIdx.x;
  const int tid = threadIdx.x;
  if (blk < 2048) {
    int i = (blk * 256 + tid) * 8;
    float4 a = *(const float4*)(x + i);
    float4 b = *(const float4*)(x + i + 4);
    short8 v;
    v[0] = (short)f2bf(a.x); v[1] = (short)f2bf(a.y);
    v[2] = (short)f2bf(a.z); v[3] = (short)f2bf(a.w);
    v[4] = (short)f2bf(b.x); v[5] = (short)f2bf(b.y);
    v[6] = (short)f2bf(b.z); v[7] = (short)f2bf(b.w);
    *(short8*)(xb + i) = v;
    return;
  }
  const int pb = blk - 2048;
  const int z = pb >> 10;
  const int xy = pb & 1023;
  const int n0 = (xy & 31) * 32, k0 = (xy >> 5) * 32;
  const int tx = tid & 31, ty = tid >> 5;          // 32 x 8
  const float* src = (z == 0) ? Wq : (z == 1) ? Wk : (z == 2) ? Wv : Wo;
  float w0 = 0.f, w1 = 0.f, w2 = 0.f, w3 = 0.f;
  if (z == 1) {
    float a = qw[0], b = qw[1], c = qw[2], d = qw[3];
    float mx = fmaxf(fmaxf(a, b), fmaxf(c, d));
    float ea = expf(a - mx), eb = expf(b - mx), ec = expf(c - mx), ed = expf(d - mx);
    float s = ea + eb + ec + ed;
    w0 = ea / s; w1 = eb / s; w2 = ec / s; w3 = ed / s;
  }
  #pragma unroll
  for (int i = 0; i < 32; i += 8) {
    int k = k0 + ty + i;
    int n = n0 + tx;
    float v;
    if (z == 1) {
      int c = n & 63;
      if (c < 32) v = w0 * src[k * 1024 + n]      + w1 * src[k * 1024 + n + 32];
      else        v = w2 * src[k * 1024 + n - 32] + w3 * src[k * 1024 + n];
    } else {
      v = src[k * 1024 + n];
    }
    tile[ty + i][tx] = v;
  }
  __syncthreads();
  #pragma unroll
  for (int i = 0; i < 32; i += 8) {
    int n = n0 + ty + i;
    int k = k0 + tx;
    u16 v = f2bf(tile[tx][ty + i]);
    if (z < 3) Wcat[(size_t)(z * 1024 + n) * 1024 + k] = v;
    else       Wot[(size_t)n * 1024 + k] = v;
  }
}

// ---------------- GEMM (R7/R13/R15-proven): tri-buffered counted-vmcnt pipeline, BK=32 ----------------
template<int MODE, int BM>
__global__ __launch_bounds__(256, 2)
void gemm_k(const u16* __restrict__ A, const u16* __restrict__ Bm,
            u16* __restrict__ out_q, u16* __restrict__ out_k,
            u16* __restrict__ out_vt, float* __restrict__ out_f) {
  constexpr int WM = BM / 2;
  constexpr int MR = WM / 16;
  constexpr int RW = BM / 4;
  __shared__ u16 At[3][BM * 32];
  __shared__ u16 Bt[3][128 * 32];
  const int tid = threadIdx.x;
  const int wid = tid >> 6, lane = tid & 63;
  const int l15 = lane & 15, l4 = lane >> 4;

  const int nwg = gridDim.x * gridDim.y;
  const int cpx = nwg >> 3;
  int bid = blockIdx.y * gridDim.x + blockIdx.x;
  int wg = (bid & 7) * cpx + (bid >> 3);
  const int bx = wg % gridDim.x, by = wg / gridDim.x;
  const int mblk = by * BM, nblk = bx * 128;
  const int wm = (wid >> 1) * WM, wn = (wid & 1) * 64;
  f32x4 acc[MR][4] = {};

  const int rr = lane >> 2;
  const int cA = (lane & 3) * 8;
  const u16* gB = Bm + (size_t)(nblk + wid * 32 + rr) * 1024 + cA;
  const u16* gA = A + (size_t)(mblk + wid * RW + rr) * 1024 + cA;

  auto STAGE = [&](int ib, int kt) {
    #pragma unroll
    for (int q = 0; q < RW / 16; ++q)
      gload16(gA + (size_t)q * 16 * 1024 + kt, &At[ib][(wid * RW + q * 16) * 32]);
    #pragma unroll
    for (int q = 0; q < 2; ++q)
      gload16(gB + (size_t)q * 16 * 1024 + kt, &Bt[ib][(wid * 32 + q * 16) * 32]);
  };

  STAGE(0, 0);
  STAGE(1, 32);
  int ib = 0, ibw = 2;
  for (int s = 0; s < 32; ++s) {
    if (s < 31) {
      if constexpr (BM == 128) wait_vm4();
      else wait_vm3();
    } else wait_vm0();
    barrier_raw();
    if (s + 2 < 32) STAGE(ibw, (s + 2) * 32);
    short8 af[MR], bf[4];
    #pragma unroll
    for (int i = 0; i < MR; ++i)
      af[i] = *(const short8*)(&At[ib][(wm + i * 16 + l15) * 32 + l4 * 8]);
    #pragma unroll
    for (int j = 0; j < 4; ++j)
      bf[j] = *(const short8*)(&Bt[ib][(wn + j * 16 + l15) * 32 + l4 * 8]);
    #pragma unroll
    for (int i = 0; i < MR; ++i)
      #pragma unroll
      for (int j = 0; j < 4; ++j)
        acc[i][j] = __builtin_amdgcn_mfma_f32_16x16x32_bf16(af[i], bf[j], acc[i][j], 0, 0, 0);
    ib = (ib == 2) ? 0 : ib + 1;
    ibw = (ibw == 2) ? 0 : ibw + 1;
  }

  const float QSCALE = 0.17677669529663687f * 1.4426950408889634f; // 32^-0.5 * log2(e)
  #pragma unroll
  for (int i = 0; i < MR; ++i) {
    int m_g = mblk + wm + i * 16 + l4 * 4;
    #pragma unroll
    for (int j = 0; j < 4; ++j) {
      int n_g = nblk + wn + j * 16 + l15;
      f32x4 v = acc[i][j];
      if (MODE == 1) {
        #pragma unroll
        for (int jj = 0; jj < 4; ++jj)
          out_f[(size_t)(m_g + jj) * 1024 + n_g] = v[jj];
      } else {
        if (n_g < 2048) {
          u16* dst; float sc;
          if (n_g < 1024) { dst = out_q; sc = QSCALE; } else { dst = out_k; sc = 1.0f; }
          int nn = n_g & 1023;
          #pragma unroll
          for (int jj = 0; jj < 4; ++jj)
            dst[(size_t)(m_g + jj) * 1024 + nn] = f2bf(v[jj] * sc);
        } else {
          int c = n_g - 2048;
          int b = m_g >> 11, t = m_g & 2047;
          short4v p;
          p[0] = (short)f2bf(v[0]); p[1] = (short)f2bf(v[1]);
          p[2] = (short)f2bf(v[2]); p[3] = (short)f2bf(v[3]);
          *(short4v*)(out_vt + ((size_t)((b << 4) + (c >> 6)) * 64 + (c & 63)) * 2048 + t) = p;
        }
      }
    }
  }
}

// ---------------- flash attention (R15-proven): no-max + split-KV 2-way ----------------
__global__ __launch_bounds__(256, 4)
void attn_k(const u16* __restrict__ Q, const u16* __restrict__ Kb,
            const u16* __restrict__ Vt, u16* __restrict__ Opart,
            float* __restrict__ L) {
  __shared__ u16 lk[2][64 * 64];
  __shared__ u16 lv[2][64 * 64];
  const int tid = threadIdx.x, wid = tid >> 6, lane = tid & 63;
  const int l31 = lane & 31, hi = lane >> 5;

  int bid = blockIdx.y * 16 + blockIdx.x;
  int wg = (bid & 7) * 128 + (bid >> 3);
  const int qt = wg & 15;
  const int yy = wg >> 4;
  const int half = yy & 1, bh = yy >> 1;
  const int b = bh >> 4, h = bh & 15;
  const int qrow = qt * 128 + wid * 32 + l31;

  short8 qf[4];
  #pragma unroll
  for (int cs = 0; cs < 4; ++cs)
    qf[cs] = *(const short8*)(Q + (size_t)(b * 2048 + qrow) * 1024 + h * 64 + cs * 16 + hi * 8);
  #pragma unroll
  for (int cs = 0; cs < 4; ++cs) keep8(qf[cs]);

  const int sr = lane >> 3;
  const int sc8 = (lane & 7) ^ sr;
  const u16* Kg = Kb + ((size_t)b * 2048 + half * 1024) * 1024 + h * 64 + sc8 * 8;
  const u16* Vg = Vt + (size_t)bh * 64 * 2048 + half * 1024 + sc8 * 8;
  const int s0i = wid * 2;
  const int swz = l31 & 7;

  short8 onesf;
  #pragma unroll
  for (int j = 0; j < 8; ++j) onesf[j] = (short)0x3F80;
  const f32x16 z16 = {};

  f32x16 accO0 = {}, accO1 = {}, sacc = {};

  auto STAGE = [&](int tt, int ibx) {
    #pragma unroll
    for (int s2 = 0; s2 < 2; ++s2) {
      int s = s0i + s2;
      int r = s * 8 + sr;
      gload16(Kg + (size_t)(tt * 64 + r) * 1024, &lk[ibx][s * 512]);
      gload16(Vg + (size_t)r * 2048 + tt * 64, &lv[ibx][s * 512]);
    }
  };

  STAGE(0, 0);

  for (int t = 0; t < 16; ++t) {
    wait_vm0();
    barrier_raw();
    if (t + 1 < 16) STAGE(t + 1, (t + 1) & 1);

    const u16* kb = lk[t & 1];
    const u16* vb = lv[t & 1];

    f32x16 s0v, s1v;
    __builtin_amdgcn_s_setprio(1);
    {
      short8 k0 = *(const short8*)(kb + l31 * 64 + ((hi ^ swz) * 8));
      short8 k1 = *(const short8*)(kb + (32 + l31) * 64 + ((hi ^ swz) * 8));
      s0v = __builtin_amdgcn_mfma_f32_32x32x16_bf16(k0, qf[0], z16, 0, 0, 0);
      s1v = __builtin_amdgcn_mfma_f32_32x32x16_bf16(k1, qf[0], z16, 0, 0, 0);
    }
    #pragma unroll
    for (int cs = 1; cs < 4; ++cs) {
      int ch = cs * 2 + hi;
      short8 k0 = *(const short8*)(kb + l31 * 64 + ((ch ^ swz) * 8));
      short8 k1 = *(const short8*)(kb + (32 + l31) * 64 + ((ch ^ swz) * 8));
      s0v = __builtin_amdgcn_mfma_f32_32x32x16_bf16(k0, qf[cs], s0v, 0, 0, 0);
      s1v = __builtin_amdgcn_mfma_f32_32x32x16_bf16(k1, qf[cs], s1v, 0, 0, 0);
    }
    __builtin_amdgcn_s_setprio(0);

    #pragma unroll
    for (int i = 0; i < 16; ++i) { s0v[i] = fexp2(s0v[i]); s1v[i] = fexp2(s1v[i]); }

    short8 paS[4];
    #pragma unroll
    for (int hf = 0; hf < 2; ++hf) {
      #pragma unroll
      for (int kq = 0; kq < 2; ++kq) {
        float p0, p1, p2, p3, p4, p5, p6, p7;
        if (hf == 0) {
          p0 = s0v[kq*8+0]; p1 = s0v[kq*8+1]; p2 = s0v[kq*8+2]; p3 = s0v[kq*8+3];
          p4 = s0v[kq*8+4]; p5 = s0v[kq*8+5]; p6 = s0v[kq*8+6]; p7 = s0v[kq*8+7];
        } else {
          p0 = s1v[kq*8+0]; p1 = s1v[kq*8+1]; p2 = s1v[kq*8+2]; p3 = s1v[kq*8+3];
          p4 = s1v[kq*8+4]; p5 = s1v[kq*8+5]; p6 = s1v[kq*8+6]; p7 = s1v[kq*8+7];
        }
        u32 A = cvtpk(p0, p1), B = cvtpk(p2, p3);
        u32 C = cvtpk(p4, p5), D = cvtpk(p6, p7);
        plswap(A, C);
        plswap(B, D);
        u32x4 w; w[0] = A; w[1] = B; w[2] = C; w[3] = D;
        paS[hf * 2 + kq] = as_short8(w);
      }
    }

    __builtin_amdgcn_s_setprio(1);
    #pragma unroll
    for (int ks = 0; ks < 4; ++ks) {
      int ch = ks * 2 + hi;
      short8 v0 = *(const short8*)(vb + l31 * 64 + ((ch ^ swz) * 8));
      short8 v1 = *(const short8*)(vb + (32 + l31) * 64 + ((ch ^ swz) * 8));
      accO0 = __builtin_amdgcn_mfma_f32_32x32x16_bf16(v0, paS[ks], accO0, 0, 0, 0);
      accO1 = __builtin_amdgcn_mfma_f32_32x32x16_bf16(v1, paS[ks], accO1, 0, 0, 0);
      sacc  = __builtin_amdgcn_mfma_f32_32x32x16_bf16(onesf, paS[ks], sacc, 0, 0, 0);
    }
    __builtin_amdgcn_s_setprio(0);
  }

  u16* Po = Opart + (size_t)(half * 4096 + b * 2048 + qrow) * 1024 + h * 64;
  #pragma unroll
  for (int g = 0; g < 4; ++g) {
    u32x2 pr;
    pr[0] = cvtpk(accO0[4*g],    accO0[4*g+1]);
    pr[1] = cvtpk(accO0[4*g+2],  accO0[4*g+3]);
    *(u32x2*)(Po + 8*g + 4*hi) = pr;
    u32x2 pr2;
    pr2[0] = cvtpk(accO1[4*g],   accO1[4*g+1]);
    pr2[1] = cvtpk(accO1[4*g+2], accO1[4*g+3]);
    *(u32x2*)(Po + 32 + 8*g + 4*hi) = pr2;
  }
  if (hi == 0)
    L[(size_t)(half * 32 + bh) * 2048 + qrow] = sacc[0];
}

// ---------------- merge (R15-proven): linear combine of the two KV-halves ----------------
__global__ __launch_bounds__(256)
void merge_k(const u16* __restrict__ Opart, const float* __restrict__ L,
             u16* __restrict__ Ob) {
  int i = blockIdx.x * 256 + threadIdx.x;
  int e = i * 8;
  int row = e >> 10;
  int col = e & 1023;
  int h = col >> 6;
  int b = row >> 11;
  int tr = row & 2047;
  int bh = b * 16 + h;
  float l1 = L[(size_t)bh * 2048 + tr];
  float l2 = L[(size_t)(32 + bh) * 2048 + tr];
  float inv = 1.0f / (l1 + l2);
  short8 o1 = *(const short8*)(Opart + (size_t)row * 1024 + col);
  short8 o2 = *(const short8*)(Opart + (size_t)(4096 + row) * 1024 + col);
  u32x4 w;
  #pragma unroll
  for (int j = 0; j < 4; ++j) {
    float lo = (bf2f(o1[2*j])   + bf2f(o2[2*j]))   * inv;
    float hi_ = (bf2f(o1[2*j+1]) + bf2f(o2[2*j+1])) * inv;
    w[j] = cvtpk(lo, hi_);
  }
  *(u32x4*)(Ob + (size_t)row * 1024 + col) = w;
}

// ---------------- launch ----------------
// ws layout (43 MB, liveness-overlapped; R15-proven):
//  [0,2)   Wot        (prep -> gemm1)
//  [2,10)  Qb         (gemm0 -> attn)  ... reused as Ob (merge -> gemm1)
//  [10,18) Kb         (gemm0 -> attn)
//  [18,26) Vtb        (gemm0 -> attn)
//  [26,34) xb         (cvt -> gemm0)   ... reused by Opart
//  [34,40) Wcat       (prep -> gemm0)  ... reused by Opart
//  [26,42) Opart bf16 (attn -> merge)
//  [42,43) L f32      (attn -> merge)
extern "C" void kernel_launch(void* const* d_in, const int* in_sizes, int n_in,
                              void* d_out, int out_size, void* d_ws, size_t ws_size,
                              hipStream_t stream) {
  const float* x  = (const float*)d_in[0];
  const float* Wq = (const float*)d_in[1];
  const float* Wk = (const float*)d_in[2];
  const float* Wv = (const float*)d_in[3];
  const float* Wo = (const float*)d_in[4];
  const float* qw = (const float*)d_in[5];

  char* w = (char*)d_ws;
  u16* Wot   = (u16*)(w);
  u16* Qb    = (u16*)(w + (2u  << 20));
  u16* Kb    = (u16*)(w + (10u << 20));
  u16* Vtb   = (u16*)(w + (18u << 20));
  u16* xb    = (u16*)(w + (26u << 20));
  u16* Wcat  = (u16*)(w + (34u << 20));
  u16* Opart = (u16*)(w + (26u << 20));
  float* L   = (float*)(w + (42u << 20));
  u16* Ob    = Qb;   // reuse after attn

  cvtprep_kernel<<<6144, 256, 0, stream>>>(x, xb, Wq, Wk, Wv, Wo, qw, Wcat, Wot);
  gemm_k<0, 128><<<dim3(24, 32), 256, 0, stream>>>(xb, Wcat, Qb, Kb, Vtb, nullptr);
  attn_k<<<dim3(16, 64), 256, 0, stream>>>(Qb, Kb, Vtb, Opart, L);
  merge_k<<<2048, 256, 0, stream>>>(Opart, L, Ob);
  gemm_k<1, 64><<<dim3(8, 64), 256, 0, stream>>>(Ob, Wot, nullptr, nullptr, nullptr, (float*)d_out);
}